// Round 16
// baseline (7008.486 us; speedup 1.0000x reference)
//
#include <hip/hip_runtime.h>
#include <hip/hip_bf16.h>
#include <stdint.h>

#define B_   512
#define H_   1024
#define T_   144
#define NG   4096
#define NOUT 17

typedef __bf16 bf16_t;
typedef __bf16 bf16x8 __attribute__((ext_vector_type(8)));
typedef float  f32x4  __attribute__((ext_vector_type(4)));

__device__ __host__ __forceinline__ int npack(int n) {
  int g = n >> 10, j = n & 1023;
  return ((j >> 4) << 6) + (g << 4) + (j & 15);
}
__device__ __forceinline__ float sigf(float x) { return 1.f / (1.f + __expf(-x)); }
__device__ __forceinline__ float tanhf_(float x) { return 1.f - 2.f / (__expf(2.f * x) + 1.f); }

// ---------------- prep kernels (r12 plain layout, proven) ----------------

__global__ void k_pack_wA(const float* __restrict__ Whh0, bf16_t* __restrict__ PB1) {
  int idx = blockIdx.x * 256 + threadIdx.x;     // 4096*128
  int n = idx >> 7, kc = idx & 127;
  const float* s = Whh0 + (size_t)n * H_ + kc * 8;
  bf16x8 v;
#pragma unroll
  for (int e = 0; e < 8; ++e) v[e] = (bf16_t)s[e];
  int np = npack(n), jt = np >> 7, row = np & 127;
  *(bf16x8*)(PB1 + (size_t)jt * 131072 + (kc >> 2) * 4096 + row * 32 + (kc & 3) * 8) = v;
}

__global__ void k_pack_wB(const float* __restrict__ Wih1, const float* __restrict__ Whh1,
                          bf16_t* __restrict__ PB2) {
  int idx = blockIdx.x * 256 + threadIdx.x;     // 4096*256
  int n = idx >> 8, kc = idx & 255;
  int k = kc * 8;
  const float* s = (k < H_) ? (Wih1 + (size_t)n * H_ + k) : (Whh1 + (size_t)n * H_ + (k - H_));
  bf16x8 v;
#pragma unroll
  for (int e = 0; e < 8; ++e) v[e] = (bf16_t)s[e];
  int np = npack(n), jt = np >> 7, row = np & 127;
  *(bf16x8*)(PB2 + (size_t)jt * 262144 + (kc >> 2) * 4096 + row * 32 + (kc & 3) * 8) = v;
}

__global__ void k_G(const float* __restrict__ Wih0, const float* __restrict__ ffW,
                    const float* __restrict__ ffb, float* __restrict__ G) {
  int n = blockIdx.x * 256 + threadIdx.x;       // 4096
  float acc[33];
#pragma unroll
  for (int c = 0; c < 33; ++c) acc[c] = 0.f;
  for (int k = 0; k < 512; ++k) {
    float wv = Wih0[(size_t)n * H_ + 512 + k];
    const float* fr = ffW + (size_t)k * 32;
#pragma unroll
    for (int c = 0; c < 32; ++c) acc[c] += wv * fr[c];
    acc[32] += wv * ffb[k];
  }
  for (int c = 0; c < 33; ++c) G[(size_t)c * NG + n] = acc[c];
}

__global__ void k_CHp(const float* __restrict__ cond, const float* __restrict__ G,
                      const float* __restrict__ bih0, const float* __restrict__ bhh0,
                      float* __restrict__ CHp) {
  int idx = blockIdx.x * 256 + threadIdx.x;     // 512*4096
  int b = idx >> 12, n = idx & 4095;
  float acc = bih0[n] + bhh0[n] + G[(size_t)32 * NG + n];
  const float* cb = cond + (size_t)b * 32;
#pragma unroll
  for (int c = 0; c < 32; ++c) acc += cb[c] * G[(size_t)c * NG + n];
  CHp[(size_t)b * NG + npack(n)] = acc;
}

__global__ void k_E16(const float* __restrict__ emb, const float* __restrict__ Wih0,
                      float* __restrict__ E16p) {
  int idx = blockIdx.x * 256 + threadIdx.x;     // 16*4096
  int a = idx & 15, n = idx >> 4;
  const float* er = emb + (size_t)a * 511;
  const float* wr = Wih0 + (size_t)n * H_;
  float acc = 0.f;
  for (int k = 0; k < 511; ++k) acc += er[k] * wr[k];
  E16p[(size_t)a * NG + npack(n)] = acc;
}

__global__ void k_misc(const float* __restrict__ Wih0, const float* __restrict__ bih,
                       const float* __restrict__ bhh, const float* __restrict__ fcW,
                       bf16_t* __restrict__ fcWp, float* __restrict__ biasBp,
                       float* __restrict__ wcolp) {
  int idx = blockIdx.x * 256 + threadIdx.x;     // 17408
  if (idx < NG) {
    int np = npack(idx);
    biasBp[np] = bih[NG + idx] + bhh[NG + idx];
    wcolp[np]  = Wih0[(size_t)idx * H_ + 511];
  }
  if (idx < 17 * H_) fcWp[idx] = (bf16_t)fcW[idx];
}

__global__ void k_init(const float* __restrict__ h0,
                       bf16_t* __restrict__ pah0i, bf16_t* __restrict__ pah1a) {
  int idx = blockIdx.x * 256 + threadIdx.x;     // 512*128
  int b = idx >> 7, kc = idx & 127;
  const float* s0 = h0 + (size_t)b * H_ + kc * 8;
  const float* s1 = s0 + (size_t)B_ * H_;
  bf16x8 v0, v1;
#pragma unroll
  for (int e = 0; e < 8; ++e) { v0[e] = (bf16_t)s0[e]; v1[e] = (bf16_t)s1[e]; }
  size_t po = (size_t)(kc >> 2) * 16384 + b * 32 + (kc & 3) * 8;
  *(bf16x8*)(pah0i + po) = v0;
  *(bf16x8*)(pah1a + po) = v1;
}

__global__ void k_out(const float* __restrict__ preds, const float* __restrict__ fcb,
                      float* __restrict__ out) {
  int idx = blockIdx.x * 256 + threadIdx.x;     // T*B
  if (idx >= T_ * B_) return;
  int t = idx % T_, b = idx / T_;
  const float* pr = preds + ((size_t)t * B_ + b) * NOUT;
  float v[NOUT];
#pragma unroll
  for (int o = 0; o < NOUT; ++o) v[o] = pr[o] + fcb[o];
  float m = v[0];
#pragma unroll
  for (int o = 1; o < 16; ++o) m = fmaxf(m, v[o]);
  float s = 0.f;
#pragma unroll
  for (int o = 0; o < 16; ++o) s += expf(v[o] - m);
  float lse = m + logf(s);
  float* dst = out + ((size_t)b * T_ + t) * NOUT;
#pragma unroll
  for (int o = 0; o < 16; ++o) dst[o] = v[o] - lse;
  float x = v[16];
  dst[16] = (x > 0.f) ? -log1pf(expf(-x)) : (x - log1pf(expf(x)));
}

// ---------------- main persistent kernel ----------------

struct Params {
  const int* acts; const float* durs;
  const bf16_t* PB1; const bf16_t* PB2;
  const float* CHp; const float* E16p; const float* wcolp; const float* biasBp;
  const bf16_t* fcW;
  const float* c0in;
  const bf16_t* pah0i;
  bf16_t* pah0a; bf16_t* pah0b; bf16_t* pah1a; bf16_t* pah1b;
  unsigned* slots; float* preds;
};

__device__ __forceinline__ void gbar(unsigned* slots, unsigned phase, int tid, int wg) {
  __syncthreads();
  if (tid == 0) {
    __builtin_amdgcn_fence(__ATOMIC_RELEASE, "agent");
    __hip_atomic_store(slots + (size_t)wg * 16, phase, __ATOMIC_RELAXED, __HIP_MEMORY_SCOPE_AGENT);
  }
  {
    const unsigned* a0 = slots + (size_t)tid * 16;
    while (__hip_atomic_load(a0, __ATOMIC_RELAXED, __HIP_MEMORY_SCOPE_SYSTEM) < phase)
      __builtin_amdgcn_s_sleep(1);
  }
  __syncthreads();
}

struct BS { bf16x8 b[4], c[4], d[4]; };          // 12 B-frags (48 VGPR)
struct PS { bf16x8 a0, a1, b0, b1, b2, b3; };    // prologue slot

#define VMW(N) { asm volatile("s_waitcnt vmcnt(" #N ")" ::: "memory"); \
                 __builtin_amdgcn_sched_barrier(0); }
#define LGK0   { asm volatile("s_waitcnt lgkmcnt(0)" ::: "memory"); \
                 __builtin_amdgcn_sched_barrier(0); }
#define WGBAR  { __builtin_amdgcn_s_barrier(); __builtin_amdgcn_sched_barrier(0); }

#define MFM(ACC, AV, BV) ACC = __builtin_amdgcn_mfma_f32_16x16x32_bf16(AV, BV, ACC, 0, 0, 0)

__device__ __forceinline__ void ldB4(bf16x8* r, const char* p) {
  asm volatile("global_load_dwordx4 %0, %4, off\n\t"
               "global_load_dwordx4 %1, %4, off offset:1024\n\t"
               "global_load_dwordx4 %2, %4, off offset:2048\n\t"
               "global_load_dwordx4 %3, %4, off offset:3072"
               : "=&v"(r[0]), "=&v"(r[1]), "=&v"(r[2]), "=&v"(r[3]) : "v"(p));
}

__global__ __launch_bounds__(256, 1) void lstm_main(Params p) {
  __shared__ __align__(16) char smem[3 * 8192];   // 3 A-panel bufs (64 rows x 128B)

  const int tid = threadIdx.x;
  const int w = tid >> 6, l = tid & 63;
  const int wg = blockIdx.x;                  // 256 WGs
  const int mt2 = wg >> 5;                    // 8 M-tiles of 64 rows
  const int jt  = ((wg >> 3) & 3) * 8 + (wg & 7);   // 32 jt (4 per XCD)
  const int jj = l & 15, rq = l >> 4;
  const int mh = w >> 1;                      // wave role: m-half (32 rows)
  const int st = w & 1;                       // wave role: 16-col strip
  const int bfrag = st * 4096 + jj * 64 + rq * 16;
  const char* B1 = (const char*)p.PB1 + (size_t)jt * 262144;
  const char* B2 = (const char*)p.PB2 + (size_t)jt * 524288;
  const int heb = jt * 16384 + st * 16 + jj;
  const int npb = (jt * 2 + st) * 64;

  // A-stage mapping: thread stages 32B of the 8KB A-panel (h0 64 rows + h1 64 rows)
  const int sh    = tid >> 7;                 // 0 = h0, 1 = h1
  const int srow  = tid & 63;
  const int shalf = (tid >> 6) & 1;
  const int g_aoff = (mt2 * 64 + srow) * 64 + shalf * 32;
  const int lwr = srow * 128;
  const int ws0 = ((sh * 4 + shalf * 2 + 0) ^ (srow & 7)) * 16;
  const int ws1 = ((sh * 4 + shalf * 2 + 1) ^ (srow & 7)) * 16;
  // read addrs: h0 frag slot rq, h1 frag slot 4+rq, rows mh*32+{jj, 16+jj}
  const int r00 = (mh * 32 + jj) * 128 + (((0 + rq) ^ (jj & 7)) * 16);
  const int r01 = (mh * 32 + jj) * 128 + (((4 + rq) ^ (jj & 7)) * 16);
  const int r10 = r00 + 2048;
  const int r11 = r01 + 2048;

  bf16x8 fcw_a, fcw_b, fw16_a, fw16_b;
  {
    const char* fwp = (const char*)p.fcW;
    fcw_a  = *(const bf16x8*)(fwp + jj * 2048 + (jt * 2 + st) * 32);
    fcw_b  = *(const bf16x8*)(fwp + jj * 2048 + (jt * 2 + st) * 32 + 16);
    fw16_a = *(const bf16x8*)(fwp + 16 * 2048 + (jt * 2 + st) * 32);
    fw16_b = *(const bf16x8*)(fwp + 16 * 2048 + (jt * 2 + st) * 32 + 16);
  }

  float chv[2][4][4], cv0[2][4], cv1[2][4], bzv[4], wcv[4];
#pragma unroll
  for (int m = 0; m < 2; ++m)
#pragma unroll
    for (int qq = 0; qq < 4; ++qq) {
      int b = mt2 * 64 + mh * 32 + m * 16 + rq * 4 + qq;
      int jcol = (jt * 2 + st) * 16 + jj;
      cv0[m][qq] = p.c0in[(size_t)b * H_ + jcol];
      cv1[m][qq] = p.c0in[(size_t)B_ * H_ + (size_t)b * H_ + jcol];
#pragma unroll
      for (int g = 0; g < 4; ++g)
        chv[m][qq][g] = p.CHp[(size_t)b * NG + npb + g * 16 + jj];
    }
#pragma unroll
  for (int g = 0; g < 4; ++g) {
    bzv[g] = p.biasBp[npb + g * 16 + jj];
    wcv[g] = p.wcolp[npb + g * 16 + jj];
  }
  VMW(0);

  unsigned phase = 0;

  // ======== prologue GEMM: h0^(0); register path (r12/r13-proven shape) ========
  {
    f32x4 accp[4][2];
#pragma unroll
    for (int g = 0; g < 4; ++g)
#pragma unroll
      for (int m = 0; m < 2; ++m) accp[g][m] = (f32x4){0.f, 0.f, 0.f, 0.f};

    const char* Ai = (const char*)p.pah0i;
    const int pa_off = (mt2 * 64 + mh * 32 + jj) * 64 + rq * 16;
    PS S0, S1, S2;
    auto Pp = [&](int kk, PS& S) {       // 6 vm-ops
      const char* pa = Ai + (size_t)kk * 32768 + pa_off;
      asm volatile("global_load_dwordx4 %0, %2, off\n\t"
                   "global_load_dwordx4 %1, %2, off offset:1024"
                   : "=&v"(S.a0), "=&v"(S.a1) : "v"(pa));
      const char* p0 = B1 + (size_t)kk * 8192 + bfrag;
      asm volatile("global_load_dwordx4 %0, %4, off\n\t"
                   "global_load_dwordx4 %1, %4, off offset:1024\n\t"
                   "global_load_dwordx4 %2, %4, off offset:2048\n\t"
                   "global_load_dwordx4 %3, %4, off offset:3072"
                   : "=&v"(S.b0), "=&v"(S.b1), "=&v"(S.b2), "=&v"(S.b3) : "v"(p0));
    };
    auto Cp = [&](const PS& S) {         // 8 MFMA
      MFM(accp[0][0], S.a0, S.b0); MFM(accp[0][1], S.a1, S.b0);
      MFM(accp[1][0], S.a0, S.b1); MFM(accp[1][1], S.a1, S.b1);
      MFM(accp[2][0], S.a0, S.b2); MFM(accp[2][1], S.a1, S.b2);
      MFM(accp[3][0], S.a0, S.b3); MFM(accp[3][1], S.a1, S.b3);
    };
    Pp(0, S0); Pp(1, S1);
#pragma unroll 1
    for (int o = 0; o < 10; ++o) {
      Pp(3 * o + 2, S2); VMW(12); Cp(S0);
      Pp(3 * o + 3, S0); VMW(12); Cp(S1);
      Pp(3 * o + 4, S1); VMW(12); Cp(S2);
    }
    VMW(6); Cp(S0);
    VMW(0); Cp(S1);

    bf16_t* H0n = p.pah0a;
#pragma unroll
    for (int m = 0; m < 2; ++m)
#pragma unroll
      for (int qq = 0; qq < 4; ++qq) {
        int b = mt2 * 64 + mh * 32 + m * 16 + rq * 4 + qq;
        float pre[4];
#pragma unroll
        for (int g = 0; g < 4; ++g)
          pre[g] = accp[g][m][qq] + chv[m][qq][g] + p.E16p[npb + g * 16 + jj];
        float cn = sigf(pre[1]) * cv0[m][qq] + sigf(pre[0]) * tanhf_(pre[2]);
        float hn = sigf(pre[3]) * tanhf_(cn);
        cv0[m][qq] = cn;
        H0n[(size_t)heb + b * 32] = (bf16_t)hn;
      }
    ++phase; gbar(p.slots, phase, tid, wg);
  }

  // ======== main loop: explicit even/odd sub-blocks, static registers ========
#pragma unroll 1
  for (int t = 0; t < T_; ++t) {
    const char* Ah0 = (const char*)((t & 1) ? p.pah0b : p.pah0a);
    bf16_t*     H0n = (t & 1) ? p.pah0a : p.pah0b;
    const char* Ah1 = (const char*)((t & 1) ? p.pah1b : p.pah1a);
    bf16_t*     H1n = (t & 1) ? p.pah1a : p.pah1b;
    const char* Asrc = sh ? Ah1 : Ah0;

    f32x4 acc0[4][2], acc1[4][2];
#pragma unroll
    for (int g = 0; g < 4; ++g)
#pragma unroll
      for (int m = 0; m < 2; ++m) {
        acc0[g][m] = (f32x4){0.f, 0.f, 0.f, 0.f};
        acc1[g][m] = (f32x4){0.f, 0.f, 0.f, 0.f};
      }

    bf16x8 Ar0a, Ar0b, Ar1a, Ar1b;       // Ar0: even kk, Ar1: odd kk
    BS Bs0, Bs1;                          // Bs0: even kk, Bs1: odd kk
    auto AST0 = [&](int kk) {
      const char* s = Asrc + (size_t)kk * 32768 + g_aoff;
      asm volatile("global_load_dwordx4 %0, %2, off sc1\n\t"
                   "global_load_dwordx4 %1, %2, off offset:16 sc1"
                   : "=&v"(Ar0a), "=&v"(Ar0b) : "v"(s));
    };
    auto AST1 = [&](int kk) {
      const char* s = Asrc + (size_t)kk * 32768 + g_aoff;
      asm volatile("global_load_dwordx4 %0, %2, off sc1\n\t"
                   "global_load_dwordx4 %1, %2, off offset:16 sc1"
                   : "=&v"(Ar1a), "=&v"(Ar1b) : "v"(s));
    };
    auto DSW0 = [&](char* buf) {          // write Ar0 (static)
      *(bf16x8*)(buf + lwr + ws0) = Ar0a;
      *(bf16x8*)(buf + lwr + ws1) = Ar0b;
    };
    auto DSW1 = [&](char* buf) {          // write Ar1 (static)
      *(bf16x8*)(buf + lwr + ws0) = Ar1a;
      *(bf16x8*)(buf + lwr + ws1) = Ar1b;
    };
    auto LBD0 = [&](int kk) {
      ldB4(Bs0.b, B1 + (size_t)kk * 8192 + bfrag);
      ldB4(Bs0.c, B2 + (size_t)kk * 8192 + bfrag);
      ldB4(Bs0.d, B2 + (size_t)(kk + 32) * 8192 + bfrag);
    };
    auto LBD1 = [&](int kk) {
      ldB4(Bs1.b, B1 + (size_t)kk * 8192 + bfrag);
      ldB4(Bs1.c, B2 + (size_t)kk * 8192 + bfrag);
      ldB4(Bs1.d, B2 + (size_t)(kk + 32) * 8192 + bfrag);
    };
    auto CMP0 = [&](const char* buf) {    // consume Bs0 (static)
      bf16x8 a0 = *(const bf16x8*)(buf + r00);
      bf16x8 a1 = *(const bf16x8*)(buf + r10);
      bf16x8 e0 = *(const bf16x8*)(buf + r01);
      bf16x8 e1 = *(const bf16x8*)(buf + r11);
      LGK0;
#pragma unroll
      for (int g = 0; g < 4; ++g) { MFM(acc0[g][0], a0, Bs0.b[g]); MFM(acc0[g][1], a1, Bs0.b[g]); }
#pragma unroll
      for (int g = 0; g < 4; ++g) { MFM(acc1[g][0], a0, Bs0.c[g]); MFM(acc1[g][1], a1, Bs0.c[g]); }
#pragma unroll
      for (int g = 0; g < 4; ++g) { MFM(acc1[g][0], e0, Bs0.d[g]); MFM(acc1[g][1], e1, Bs0.d[g]); }
    };
    auto CMP1 = [&](const char* buf) {    // consume Bs1 (static)
      bf16x8 a0 = *(const bf16x8*)(buf + r00);
      bf16x8 a1 = *(const bf16x8*)(buf + r10);
      bf16x8 e0 = *(const bf16x8*)(buf + r01);
      bf16x8 e1 = *(const bf16x8*)(buf + r11);
      LGK0;
#pragma unroll
      for (int g = 0; g < 4; ++g) { MFM(acc0[g][0], a0, Bs1.b[g]); MFM(acc0[g][1], a1, Bs1.b[g]); }
#pragma unroll
      for (int g = 0; g < 4; ++g) { MFM(acc1[g][0], a0, Bs1.c[g]); MFM(acc1[g][1], a1, Bs1.c[g]); }
#pragma unroll
      for (int g = 0; g < 4; ++g) { MFM(acc1[g][0], e0, Bs1.d[g]); MFM(acc1[g][1], e1, Bs1.d[g]); }
    };

    // pipe prologue: queue [AST0(0):2, AST1(1):2, LBD0(0):12] = 16
    AST0(0); AST1(1); LBD0(0);
    VMW(14);                               // A(0) arrived
    DSW0(smem);                            // buf0 <- A(0)
    AST0(2); LBD1(1);                      // queue 28
    LGK0; WGBAR;                           // buf0 ready
    int bufR = 0;

    // body: sub-blocks kk (even: Ar1/Bs0 pattern), kk+1 (odd: Ar0/Bs1)
#pragma unroll 1
    for (int kk = 0; kk < 28; kk += 2) {
      {  // even kk: A(kk+1) -> Ar1; B(kk) -> Bs0
        int bw = bufR + 1; if (bw == 3) bw = 0;
        VMW(26);                           // Ar1 = A(kk+1)
        DSW1(smem + bw * 8192);
        AST1(kk + 3);
        LGK0; WGBAR;
        VMW(16);                           // Bs0 = B(kk)
        CMP0(smem + bufR * 8192);
        LBD0(kk + 2);
        bufR = bw;
      }
      {  // odd kk+1: A(kk+2) -> Ar0; B(kk+1) -> Bs1
        int bw = bufR + 1; if (bw == 3) bw = 0;
        VMW(26);                           // Ar0 = A(kk+2)
        DSW0(smem + bw * 8192);
        AST0(kk + 4);
        LGK0; WGBAR;
        VMW(16);                           // Bs1 = B(kk+1)
        CMP1(smem + bufR * 8192);
        LBD1(kk + 3);
        bufR = bw;
      }
    }
    {  // kk = 28 (even, full; AST1(31) in range)
      int bw = bufR + 1; if (bw == 3) bw = 0;
      VMW(26);                             // Ar1 = A(29)
      DSW1(smem + bw * 8192);
      AST1(31);
      LGK0; WGBAR;
      VMW(16);                             // Bs0 = B(28)
      CMP0(smem + bufR * 8192);
      LBD0(30);
      bufR = bw;
    }
    {  // kk = 29 (odd; no AST)
      int bw = bufR + 1; if (bw == 3) bw = 0;
      VMW(26);                             // Ar0 = A(30)
      DSW0(smem + bw * 8192);
      LGK0; WGBAR;
      VMW(14);                             // Bs1 = B(29)
      CMP1(smem + bufR * 8192);
      LBD1(31);
      bufR = bw;
    }
    {  // kk = 30 (even; no AST, no LBD)
      int bw = bufR + 1; if (bw == 3) bw = 0;
      VMW(24);                             // Ar1 = A(31)
      DSW1(smem + bw * 8192);
      LGK0; WGBAR;
      VMW(12);                             // Bs0 = B(30)
      CMP0(smem + bufR * 8192);
      bufR = bw;
    }
    {  // kk = 31
      VMW(0);                              // Bs1 = B(31)
      CMP1(smem + bufR * 8192);
    }

    // epilogue
#pragma unroll
    for (int m = 0; m < 2; ++m)
#pragma unroll
      for (int qq = 0; qq < 4; ++qq) {
        int b = mt2 * 64 + mh * 32 + m * 16 + rq * 4 + qq;
        int act = p.acts[(size_t)b * T_ + t];
        float dur = p.durs[(size_t)b * T_ + t];
        float pre1[4];
#pragma unroll
        for (int g = 0; g < 4; ++g) pre1[g] = acc1[g][m][qq] + bzv[g];
        float cn1 = sigf(pre1[1]) * cv1[m][qq] + sigf(pre1[0]) * tanhf_(pre1[2]);
        float hn1 = sigf(pre1[3]) * tanhf_(cn1);
        cv1[m][qq] = cn1;
        H1n[(size_t)heb + b * 32] = (bf16_t)hn1;
        float pre0[4];
#pragma unroll
        for (int g = 0; g < 4; ++g)
          pre0[g] = acc0[g][m][qq] + chv[m][qq][g]
                  + p.E16p[(size_t)act * NG + npb + g * 16 + jj] + dur * wcv[g];
        float cn0 = sigf(pre0[1]) * cv0[m][qq] + sigf(pre0[0]) * tanhf_(pre0[2]);
        float hn0 = sigf(pre0[3]) * tanhf_(cn0);
        cv0[m][qq] = cn0;
        H0n[(size_t)heb + b * 32] = (bf16_t)hn0;
        float accO = 0.f, acc16 = 0.f;
        int base = l & 48;
#pragma unroll
        for (int sc = 0; sc < 8; ++sc) {
          float hs = __shfl(hn1, base | sc, 64);
          accO  += hs * (float)fcw_a[sc];
          acc16 += hs * (float)fw16_a[sc];
        }
#pragma unroll
        for (int sc = 0; sc < 8; ++sc) {
          float hs = __shfl(hn1, base | (8 + sc), 64);
          accO  += hs * (float)fcw_b[sc];
          acc16 += hs * (float)fw16_b[sc];
        }
        float* pb = p.preds + ((size_t)t * B_ + b) * NOUT;
        atomicAdd(pb + jj, accO);
        if (jj == 15) atomicAdd(pb + 16, acc16);
      }
    ++phase; gbar(p.slots, phase, tid, wg);
  }
}

// ---------------- launch ----------------

extern "C" void kernel_launch(void* const* d_in, const int* in_sizes, int n_in,
                              void* d_out, int out_size, void* d_ws, size_t ws_size,
                              hipStream_t stream) {
  (void)in_sizes; (void)n_in; (void)out_size; (void)ws_size;
  const float* h0   = (const float*)d_in[1];
  const float* c0   = (const float*)d_in[2];
  const float* cond = (const float*)d_in[3];
  const int*   acts = (const int*)d_in[4];
  const float* durs = (const float*)d_in[5];
  const float* emb  = (const float*)d_in[6];
  const float* ffW  = (const float*)d_in[7];
  const float* ffb  = (const float*)d_in[8];
  const float* Wih  = (const float*)d_in[9];
  const float* Whh  = (const float*)d_in[10];
  const float* bih  = (const float*)d_in[11];
  const float* bhh  = (const float*)d_in[12];
  const float* fcW  = (const float*)d_in[13];
  const float* fcb  = (const float*)d_in[14];

  char* ws = (char*)d_ws;
  size_t off = 0;
  auto alloc = [&](size_t bytes) -> char* {
    char* p0 = ws + off;
    off = (off + bytes + 255) & ~(size_t)255;
    return p0;
  };
  unsigned* slots = (unsigned*)alloc(256 * 64);
  bf16_t* PB1     = (bf16_t*)alloc((size_t)NG * H_ * 2);
  bf16_t* PB2     = (bf16_t*)alloc((size_t)NG * 2048 * 2);
  float*  CHp     = (float*)alloc((size_t)B_ * NG * 4);
  float*  E16p    = (float*)alloc((size_t)16 * NG * 4);
  float*  wcolp   = (float*)alloc((size_t)NG * 4);
  float*  biasBp  = (float*)alloc((size_t)NG * 4);
  float*  G       = (float*)alloc((size_t)33 * NG * 4);
  bf16_t* fcWp    = (bf16_t*)alloc((size_t)17 * H_ * 2);
  bf16_t* pah0i   = (bf16_t*)alloc((size_t)B_ * H_ * 2);
  bf16_t* pah0a   = (bf16_t*)alloc((size_t)B_ * H_ * 2);
  bf16_t* pah0b   = (bf16_t*)alloc((size_t)B_ * H_ * 2);
  bf16_t* pah1a   = (bf16_t*)alloc((size_t)B_ * H_ * 2);
  bf16_t* pah1b   = (bf16_t*)alloc((size_t)B_ * H_ * 2);
  float*  preds   = (float*)alloc((size_t)T_ * B_ * NOUT * 4);

  hipMemsetAsync(slots, 0, 256 * 64, stream);
  hipMemsetAsync(preds, 0, (size_t)T_ * B_ * NOUT * 4, stream);
  k_pack_wA<<<2048, 256, 0, stream>>>(Whh, PB1);
  k_pack_wB<<<4096, 256, 0, stream>>>(Wih + (size_t)NG * H_, Whh + (size_t)NG * H_, PB2);
  k_G<<<16, 256, 0, stream>>>(Wih, ffW, ffb, G);
  k_CHp<<<8192, 256, 0, stream>>>(cond, G, bih, bhh, CHp);
  k_E16<<<256, 256, 0, stream>>>(emb, Wih, E16p);
  k_misc<<<68, 256, 0, stream>>>(Wih, bih, bhh, fcW, fcWp, biasBp, wcolp);
  k_init<<<256, 256, 0, stream>>>(h0, pah0i, pah1a);

  Params prm;
  prm.acts = acts; prm.durs = durs;
  prm.PB1 = PB1; prm.PB2 = PB2;
  prm.CHp = CHp; prm.E16p = E16p; prm.wcolp = wcolp; prm.biasBp = biasBp;
  prm.fcW = fcWp;
  prm.c0in = c0;
  prm.pah0i = pah0i;
  prm.pah0a = pah0a; prm.pah0b = pah0b; prm.pah1a = pah1a; prm.pah1b = pah1b;
  prm.slots = slots; prm.preds = preds;

  lstm_main<<<dim3(256), dim3(256), 0, stream>>>(prm);
  k_out<<<(T_ * B_ + 255) / 256, 256, 0, stream>>>(preds, fcb, (float*)d_out);
}